// Round 9
// baseline (577.319 us; speedup 1.0000x reference)
//
#include <hip/hip_runtime.h>

#define NN 100000
#define NE 1600000
constexpr float EPS_BN = 1e-5f;
constexpr float ALPHA = 0.01f;
constexpr int NBUCK = (NN + 127) / 128;     // 782 buckets of 128 nodes
constexpr int GA = 128;                     // bucket-pass blocks
constexpr int EPB = NE / GA;                // 12500 edges/block (exact)
constexpr int GX = (NN + 63) / 64;          // 1563 gemm blocks

typedef __attribute__((ext_vector_type(8))) short short8;
typedef __attribute__((ext_vector_type(4))) float f32x4;

// ---- bf16 helpers ----
__device__ __forceinline__ float bfu2f(uint lo16) {
    union { uint i; float f; } v; v.i = lo16 << 16; return v.f;
}
__device__ __forceinline__ float bfhi2f(uint u) {
    union { uint i; float f; } v; v.i = u & 0xffff0000u; return v.f;
}
__device__ __forceinline__ ushort f2bf(float f) {     // RNE
    union { float f; uint i; } v; v.f = f;
    return (ushort)((v.i + 0x7fffu + ((v.i >> 16) & 1u)) >> 16);
}

// ================= bucketed CSR build =================
__global__ __launch_bounds__(256) void k_bhist(const int* __restrict__ dstv, int* __restrict__ bcnt) {
    __shared__ int hist[NBUCK];
    for (int i = threadIdx.x; i < NBUCK; i += 256) hist[i] = 0;
    __syncthreads();
    int base = blockIdx.x * EPB;
    for (int i = threadIdx.x; i < EPB; i += 256)
        atomicAdd(&hist[dstv[base + i] >> 7], 1);
    __syncthreads();
    for (int i = threadIdx.x; i < NBUCK; i += 256)
        bcnt[blockIdx.x * NBUCK + i] = hist[i];
}

__global__ __launch_bounds__(256) void k_btot(const int* __restrict__ bcnt, int* __restrict__ tot) {
    int b = blockIdx.x * 256 + threadIdx.x;
    if (b < NBUCK) {
        int t = 0;
        for (int k = 0; k < GA; ++k) t += bcnt[k * NBUCK + b];
        tot[b] = t;
    }
}

__global__ __launch_bounds__(1024) void k_bscanT(const int* __restrict__ tot, int* __restrict__ bbase) {
    __shared__ int tmp[1024];
    int b = threadIdx.x;
    int v = (b < NBUCK) ? tot[b] : 0;
    tmp[b] = v;
    __syncthreads();
    for (int off = 1; off < 1024; off <<= 1) {
        int u = (b >= off) ? tmp[b - off] : 0;
        __syncthreads();
        tmp[b] += u;
        __syncthreads();
    }
    if (b < NBUCK) bbase[b] = tmp[b] - v;
    if (b == 0) bbase[NBUCK] = NE;
}

__global__ __launch_bounds__(256) void k_bcur(const int* __restrict__ bcnt, const int* __restrict__ bbase,
                                              int* __restrict__ gcur) {
    int b = blockIdx.x * 256 + threadIdx.x;
    if (b < NBUCK) {
        int cur = bbase[b];
        for (int k = 0; k < GA; ++k) { gcur[k * NBUCK + b] = cur; cur += bcnt[k * NBUCK + b]; }
    }
}

__global__ __launch_bounds__(256) void k_bscatter(const int* __restrict__ srcv, const int* __restrict__ dstv,
                                                  const int* __restrict__ gcur, uint* __restrict__ bpair) {
    __shared__ int lcur[NBUCK];
    for (int i = threadIdx.x; i < NBUCK; i += 256) lcur[i] = gcur[blockIdx.x * NBUCK + i];
    __syncthreads();
    int base = blockIdx.x * EPB;
    for (int i = threadIdx.x; i < EPB; i += 256) {
        int d = dstv[base + i], s = srcv[base + i];
        int slot = atomicAdd(&lcur[d >> 7], 1);
        bpair[slot] = ((uint)(d & 127) << 17) | (uint)s;
    }
}

__global__ __launch_bounds__(256) void k_bcsr(const uint* __restrict__ bpair, const int* __restrict__ bbase,
                                              int* __restrict__ col, int* __restrict__ cnt,
                                              int* __restrict__ indptr, float* __restrict__ dinv) {
    __shared__ int h[128];
    __shared__ int off[128];
    int b = blockIdx.x, t = threadIdx.x;
    int p0 = bbase[b], p1 = bbase[b + 1];
    if (t < 128) h[t] = 0;
    __syncthreads();
    for (int i = p0 + t; i < p1; i += 256)
        atomicAdd(&h[bpair[i] >> 17], 1);
    __syncthreads();
    if (t < 128) off[t] = h[t];
    __syncthreads();
    for (int o = 1; o < 128; o <<= 1) {
        int u = 0;
        if (t < 128 && t >= o) u = off[t - o];
        __syncthreads();
        if (t < 128) off[t] += u;
        __syncthreads();
    }
    if (t < 128) {
        int st = p0 + off[t] - h[t];
        int node = b * 128 + t;
        if (node < NN) {
            indptr[node] = st;
            cnt[node] = h[t];
            dinv[node] = rsqrtf((float)(h[t] + 1));   // +1 self loop
        }
        off[t] = st;
    }
    __syncthreads();
    for (int i = p0 + t; i < p1; i += 256) {
        uint u = bpair[i];
        int slot = atomicAdd(&off[u >> 17], 1);
        col[slot] = (int)(u & 0x1FFFFu);
    }
}

// ================= all weights -> bf16 transposed [M][K] =================
__global__ void k_wtrans_all(const float* __restrict__ W1, const float* __restrict__ W2,
                             const float* __restrict__ Wf, ushort* __restrict__ w1t,
                             ushort* __restrict__ w2t, ushort* __restrict__ wft) {
    int i = blockIdx.x * 256 + threadIdx.x;
    if (i < 8192) {                    // W1: 64x128 -> [128][64]
        int m = i / 64, k = i % 64;
        w1t[i] = f2bf(W1[(size_t)k * 128 + m]);
    } else if (i < 8192 + 32768) {     // W2: 128x256 -> [256][128]
        int j = i - 8192;
        int m = j / 128, k = j % 128;
        w2t[j] = f2bf(W2[(size_t)k * 256 + m]);
    } else if (i < 8192 + 32768 + 65536) {   // Wf: 256x256 -> [256][256]
        int j = i - 8192 - 32768;
        int m = j / 256, k = j % 256;
        wft[j] = f2bf(Wf[(size_t)k * 256 + m]);
    }
}

// ================= elementwise pre-passes =================
__global__ __launch_bounds__(256) void k_semb(const float* __restrict__ emb, const float* __restrict__ dinv,
                                              uint2* __restrict__ embs) {
    int i = blockIdx.x * 256 + threadIdx.x;   // uint2 index: 4 feats
    if (i >= NN * 16) return;
    int row = i >> 4;
    float dn = dinv[row];
    float4 f = ((const float4*)emb)[i];
    uint2 o;
    o.x = (uint)f2bf(f.x * dn) | ((uint)f2bf(f.y * dn) << 16);
    o.y = (uint)f2bf(f.z * dn) | ((uint)f2bf(f.w * dn) << 16);
    embs[i] = o;
}

__global__ __launch_bounds__(256) void k_x2s(const ushort* __restrict__ H1, const float* __restrict__ sc,
                                             const float* __restrict__ sh, const float* __restrict__ dinv,
                                             ushort* __restrict__ x2s) {
    int i = blockIdx.x * 256 + threadIdx.x;   // uint4 index: 8 feats
    if (i >= NN * 16) return;
    int row = i >> 4, f0 = (i & 15) * 8;
    float dn = dinv[row];
    uint4 u = ((const uint4*)H1)[i];
    uint uu[4] = {u.x, u.y, u.z, u.w};
    uint oo[4];
#pragma unroll
    for (int q = 0; q < 4; ++q) {
        int f = f0 + q * 2;
        float e0 = bfu2f(uu[q] & 0xffffu) * sc[f] + sh[f];
        float e1 = bfhi2f(uu[q]) * sc[f + 1] + sh[f + 1];
        e0 = ((e0 >= 0.f) ? e0 : ALPHA * e0) * dn;
        e1 = ((e1 >= 0.f) ? e1 : ALPHA * e1) * dn;
        oo[q] = (uint)f2bf(e0) | ((uint)f2bf(e1) << 16);
    }
    uint4 o; o.x = oo[0]; o.y = oo[1]; o.z = oo[2]; o.w = oo[3];
    ((uint4*)x2s)[i] = o;
}

// ================= fused gather + MFMA GEMM =================
// Block = 64 output nodes. Phase 1: each wave gathers 16 node-rows
// (agg = own + sum neighbors, *dinv) straight into the LDS A-tile.
// Phase 2: full-width GEMM from LDS; C = bf16/fp32(acc + bias); optional BN-stats.
// NOTE: all __shfl calls execute converged (uniform trip counts); per-lane
// variation is carried in registers (j+h), never in control flow around a shfl.
template <int K, int NOUT, int OUT, bool STATS>
__global__ __launch_bounds__(256) void k_aggmm(
        const ushort* __restrict__ X, const int* __restrict__ indptr, const int* __restrict__ cnt,
        const int* __restrict__ col, const float* __restrict__ dinv,
        const ushort* __restrict__ BT, void* __restrict__ Cp,
        const float* __restrict__ bias, float* __restrict__ partials) {
    constexpr int BM = 64, BK = 32, LDA = K + 8;
    constexpr int WN = NOUT / 4;          // wave col width
    constexpr int NF = WN / 16;           // col frags/wave
    constexpr int NT = K / BK;
    __shared__ ushort As[BM * LDA];

    int tid = threadIdx.x;
    int brow = blockIdx.x * BM;
    int lane = tid & 63, wid = tid >> 6;
    int fr = lane & 15, fq = lane >> 4;
    int fk = fq * 8;
    const uint* Xu = (const uint*)X;

    // ---- phase 1: gather 16 rows per wave into As ----
    if constexpr (K == 128) {
        for (int ni = 0; ni < 16; ++ni) {
            int node = brow + wid * 16 + ni;
            int arow = (wid * 16 + ni) * LDA;
            if (node < NN) {
                uint u = Xu[(size_t)node * 64 + lane];
                float a0 = bfu2f(u & 0xffffu), a1 = bfhi2f(u);
                float b0 = 0.f, b1 = 0.f;
                int start = indptr[node], c = cnt[node];
                for (int base = 0; base < c; base += 64) {
                    int m = min(64, c - base);
                    int colv = (lane < m) ? col[start + base + lane] : 0;
                    int j = 0;
                    for (; j + 2 <= m; j += 2) {                 // converged, uniform
                        int s0 = __shfl(colv, j), s1 = __shfl(colv, j + 1);
                        uint v0 = Xu[(size_t)s0 * 64 + lane];
                        uint v1 = Xu[(size_t)s1 * 64 + lane];
                        a0 += bfu2f(v0 & 0xffffu); a1 += bfhi2f(v0);
                        b0 += bfu2f(v1 & 0xffffu); b1 += bfhi2f(v1);
                    }
                    if (j < m) {                                 // converged tail
                        int s0 = __shfl(colv, j);
                        uint v = Xu[(size_t)s0 * 64 + lane];
                        a0 += bfu2f(v & 0xffffu); a1 += bfhi2f(v);
                    }
                }
                a0 += b0; a1 += b1;
                float dn = dinv[node];
                *(uint*)&As[arow + lane * 2] = (uint)f2bf(a0 * dn) | ((uint)f2bf(a1 * dn) << 16);
            } else {
                *(uint*)&As[arow + lane * 2] = 0;
            }
        }
    } else {   // K == 64: half-wave per row-copy, parity in REGISTERS (converged shfl)
        int t2 = lane & 31, h = lane >> 5;
        for (int ni = 0; ni < 16; ++ni) {
            int node = brow + wid * 16 + ni;
            int arow = (wid * 16 + ni) * LDA;
            if (node < NN) {
                float a0 = 0.f, a1 = 0.f;
                if (h == 0) {
                    uint u = Xu[(size_t)node * 32 + t2];
                    a0 = bfu2f(u & 0xffffu); a1 = bfhi2f(u);
                }
                int start = indptr[node], c = cnt[node];
                for (int base = 0; base < c; base += 64) {
                    int m = min(64, c - base);
                    int colv = (lane < m) ? col[start + base + lane] : 0;
                    int j = 0;
                    for (; j + 2 <= m; j += 2) {                 // converged, uniform
                        int sj = __shfl(colv, j + h);            // h=0 -> even, h=1 -> odd
                        uint v = Xu[(size_t)sj * 32 + t2];
                        a0 += bfu2f(v & 0xffffu); a1 += bfhi2f(v);
                    }
                    if (j < m) {                                 // odd tail, shfl converged
                        int sj = __shfl(colv, j);
                        if (h == 0) {
                            uint v = Xu[(size_t)sj * 32 + t2];
                            a0 += bfu2f(v & 0xffffu); a1 += bfhi2f(v);
                        }
                    }
                }
                a0 += __shfl_xor(a0, 32);
                a1 += __shfl_xor(a1, 32);
                if (h == 0) {
                    float dn = dinv[node];
                    *(uint*)&As[arow + t2 * 2] = (uint)f2bf(a0 * dn) | ((uint)f2bf(a1 * dn) << 16);
                }
            } else {
                if (h == 0) *(uint*)&As[arow + t2 * 2] = 0;
            }
        }
    }
    __syncthreads();

    // ---- phase 2: GEMM from LDS ----
    f32x4 acc[4][NF];
#pragma unroll
    for (int mi = 0; mi < 4; ++mi)
#pragma unroll
        for (int ni = 0; ni < NF; ++ni) acc[mi][ni] = (f32x4){0.f, 0.f, 0.f, 0.f};

#pragma unroll
    for (int t = 0; t < NT; ++t) {
        short8 bfv[NF];
#pragma unroll
        for (int ni = 0; ni < NF; ++ni)
            bfv[ni] = *(const short8*)(BT + (size_t)(wid * WN + ni * 16 + fr) * K + t * BK + fk);
        short8 af[4];
#pragma unroll
        for (int mi = 0; mi < 4; ++mi)
            af[mi] = *(const short8*)&As[(mi * 16 + fr) * LDA + t * BK + fk];
#pragma unroll
        for (int mi = 0; mi < 4; ++mi)
#pragma unroll
            for (int ni = 0; ni < NF; ++ni)
                acc[mi][ni] = __builtin_amdgcn_mfma_f32_16x16x32_bf16(af[mi], bfv[ni], acc[mi][ni], 0, 0, 0);
    }

    float bv[NF];
#pragma unroll
    for (int ni = 0; ni < NF; ++ni) bv[ni] = bias[wid * WN + ni * 16 + fr];

    float sv[NF], qv[NF];
#pragma unroll
    for (int ni = 0; ni < NF; ++ni) { sv[ni] = 0.f; qv[ni] = 0.f; }

#pragma unroll
    for (int mi = 0; mi < 4; ++mi)
#pragma unroll
        for (int r = 0; r < 4; ++r) {
            int row = brow + mi * 16 + fq * 4 + r;
            if (row < NN) {
#pragma unroll
                for (int ni = 0; ni < NF; ++ni) {
                    float x = acc[mi][ni][r] + bv[ni];
                    int c = wid * WN + ni * 16 + fr;
                    if constexpr (OUT == 1)
                        ((float*)Cp)[(size_t)row * NOUT + c] = x;
                    else
                        ((ushort*)Cp)[(size_t)row * NOUT + c] = f2bf(x);
                    if constexpr (STATS) { sv[ni] += x; qv[ni] += x * x; }
                }
            }
        }

    if constexpr (STATS) {
#pragma unroll
        for (int ni = 0; ni < NF; ++ni) {
            sv[ni] += __shfl_down(sv[ni], 32); qv[ni] += __shfl_down(qv[ni], 32);
            sv[ni] += __shfl_down(sv[ni], 16); qv[ni] += __shfl_down(qv[ni], 16);
        }
        if (fq == 0) {
            float* pb = partials + (size_t)blockIdx.x * 2 * NOUT;
#pragma unroll
            for (int ni = 0; ni < NF; ++ni) {
                int c = wid * WN + ni * 16 + fr;
                pb[c] = sv[ni];
                pb[NOUT + c] = qv[ni];
            }
        }
    }
}

// ================= plain MFMA GEMM (final layer): BM=64, no B-LDS, dbuf A =================
__device__ __forceinline__ uint4 xformBN(uint4 u, int kbase, const float* s_sc, const float* s_sh) {
    uint uu[4] = {u.x, u.y, u.z, u.w};
    uint oo[4];
#pragma unroll
    for (int q = 0; q < 4; ++q) {
        int kq = kbase + q * 2;
        float e0 = bfu2f(uu[q] & 0xffffu) * s_sc[kq] + s_sh[kq];
        float e1 = bfhi2f(uu[q]) * s_sc[kq + 1] + s_sh[kq + 1];
        e0 = (e0 >= 0.f) ? e0 : ALPHA * e0;
        e1 = (e1 >= 0.f) ? e1 : ALPHA * e1;
        oo[q] = (uint)f2bf(e0) | ((uint)f2bf(e1) << 16);
    }
    return make_uint4(oo[0], oo[1], oo[2], oo[3]);
}

template <int K, int NOUT>
__global__ __launch_bounds__(256) void k_mgemm(
        const ushort* __restrict__ Ap, const ushort* __restrict__ BT, float* __restrict__ Cp,
        const float* __restrict__ scale, const float* __restrict__ shift,
        const float* __restrict__ bias) {
    constexpr int BM = 64, BK = 32, LDA = 40;
    constexpr int WN = NOUT / 4;
    constexpr int NF = WN / 16;
    constexpr int NT = K / BK;
    __shared__ ushort As[2][BM * LDA];
    __shared__ float s_sc[K];
    __shared__ float s_sh[K];

    int tid = threadIdx.x;
    int brow = blockIdx.x * BM;
    int lane = tid & 63, wid = tid >> 6;
    int fr = lane & 15, fq = lane >> 4;
    int fk = fq * 8;

    const int srow = tid >> 2, sk0 = (tid & 3) * 8;
    const int grow = brow + srow;
    const bool aok = grow < NN;
    const ushort* arp = Ap + (size_t)grow * K + sk0;

    for (int i = tid; i < K; i += 256) { s_sc[i] = scale[i]; s_sh[i] = shift[i]; }
    __syncthreads();

    f32x4 acc[4][NF];
#pragma unroll
    for (int mi = 0; mi < 4; ++mi)
#pragma unroll
        for (int ni = 0; ni < NF; ++ni) acc[mi][ni] = (f32x4){0.f, 0.f, 0.f, 0.f};

    uint4 av = make_uint4(0, 0, 0, 0);
    if (aok) av = *(const uint4*)arp;
    av = xformBN(av, sk0, s_sc, s_sh);
    *(uint4*)&As[0][srow * LDA + sk0] = av;

    for (int t = 0; t < NT; ++t) {
        __syncthreads();
        uint4 anext = make_uint4(0, 0, 0, 0);
        if (t + 1 < NT && aok)
            anext = *(const uint4*)(arp + (t + 1) * BK);

        short8 bfv[NF];
#pragma unroll
        for (int ni = 0; ni < NF; ++ni)
            bfv[ni] = *(const short8*)(BT + (size_t)(wid * WN + ni * 16 + fr) * K + t * BK + fk);
        short8 af[4];
#pragma unroll
        for (int mi = 0; mi < 4; ++mi)
            af[mi] = *(const short8*)&As[t & 1][(mi * 16 + fr) * LDA + fk];
#pragma unroll
        for (int mi = 0; mi < 4; ++mi)
#pragma unroll
            for (int ni = 0; ni < NF; ++ni)
                acc[mi][ni] = __builtin_amdgcn_mfma_f32_16x16x32_bf16(af[mi], bfv[ni], acc[mi][ni], 0, 0, 0);

        if (t + 1 < NT) {
            anext = xformBN(anext, (t + 1) * BK + sk0, s_sc, s_sh);
            *(uint4*)&As[(t + 1) & 1][srow * LDA + sk0] = anext;
        }
    }

    float bv[NF];
#pragma unroll
    for (int ni = 0; ni < NF; ++ni) bv[ni] = bias[wid * WN + ni * 16 + fr];

#pragma unroll
    for (int mi = 0; mi < 4; ++mi)
#pragma unroll
        for (int r = 0; r < 4; ++r) {
            int row = brow + mi * 16 + fq * 4 + r;
            if (row < NN) {
#pragma unroll
                for (int ni = 0; ni < NF; ++ni) {
                    int c = wid * WN + ni * 16 + fr;
                    Cp[(size_t)row * NOUT + c] = acc[mi][ni][r] + bv[ni];
                }
            }
        }
}

// ================= BN reduce: partials[GX][2M] -> scale/shift =================
template <int M>
__global__ __launch_bounds__(256) void k_bnred(const float* __restrict__ partials, const float* __restrict__ g,
                                               const float* __restrict__ be, float* __restrict__ scale,
                                               float* __restrict__ shift) {
    int tid = threadIdx.x;
    int fl = tid & 15, bl = tid >> 4;
    int f = blockIdx.x * 16 + fl;
    float s = 0.f, q = 0.f;
    for (int b = bl; b < GX; b += 16) {
        s += partials[(size_t)b * 2 * M + f];
        q += partials[(size_t)b * 2 * M + M + f];
    }
    __shared__ float rs[256], rq[256];
    rs[tid] = s; rq[tid] = q;
    __syncthreads();
    for (int h = 128; h >= 16; h >>= 1) {
        if (tid < h) { rs[tid] += rs[tid + h]; rq[tid] += rq[tid + h]; }
        __syncthreads();
    }
    if (tid < 16) {
        float su = rs[tid], qu = rq[tid];
        float mu = su * (1.f / NN);
        float var = qu * (1.f / NN) - mu * mu;
        float r = rsqrtf(var + EPS_BN);
        float sc = g[f] * r;
        scale[f] = sc;
        shift[f] = be[f] - mu * sc;
    }
}

// ================= launch =================
extern "C" void kernel_launch(void* const* d_in, const int* in_sizes, int n_in,
                              void* d_out, int out_size, void* d_ws, size_t ws_size,
                              hipStream_t stream) {
    const float* emb = (const float*)d_in[0];
    const int* eidx  = (const int*)d_in[1];
    const float* W1  = (const float*)d_in[2];
    const float* b1  = (const float*)d_in[3];
    const float* g1  = (const float*)d_in[4];
    const float* be1 = (const float*)d_in[5];
    const float* W2  = (const float*)d_in[6];
    const float* b2  = (const float*)d_in[7];
    const float* g2  = (const float*)d_in[8];
    const float* be2 = (const float*)d_in[9];
    const float* Wf  = (const float*)d_in[10];
    const float* bf  = (const float*)d_in[11];
    float* out = (float*)d_out;
    const int* srcv = eidx;
    const int* dstv = eidx + NE;

    char* w = (char*)d_ws;
    auto alloc = [&](size_t bytes) {
        char* p = w;
        w += (bytes + 255) / 256 * 256;
        return p;
    };
    int* cnt    = (int*)alloc((size_t)NN * 4);
    int* indptr = (int*)alloc((size_t)NN * 4);
    int* bcnt   = (int*)alloc((size_t)NBUCK * GA * 4);
    int* gcur   = (int*)alloc((size_t)NBUCK * GA * 4);
    int* tot    = (int*)alloc((size_t)NBUCK * 4);
    int* bbase  = (int*)alloc((size_t)(NBUCK + 1) * 4);
    int* colb   = (int*)alloc((size_t)NE * 4);
    uint* bpair = (uint*)alloc((size_t)NE * 4);
    float* dinv = (float*)alloc((size_t)NN * 4);
    float* partials = (float*)alloc((size_t)GX * 512 * 4);
    float* sc1 = (float*)alloc(128 * 4);
    float* sh1 = (float*)alloc(128 * 4);
    float* sc2 = (float*)alloc(256 * 4);
    float* sh2 = (float*)alloc(256 * 4);
    ushort* w1t = (ushort*)alloc((size_t)128 * 64 * 2);
    ushort* w2t = (ushort*)alloc((size_t)256 * 128 * 2);
    ushort* wft = (ushort*)alloc((size_t)256 * 256 * 2);
    ushort* embs = (ushort*)alloc((size_t)NN * 64 * 2);
    ushort* H1   = (ushort*)alloc((size_t)NN * 128 * 2);
    ushort* x2s  = (ushort*)alloc((size_t)NN * 128 * 2);
    ushort* H2   = (ushort*)alloc((size_t)NN * 256 * 2);

    constexpr int GB4 = (NBUCK + 255) / 256;   // 4

    // ---- CSR build ----
    k_bhist<<<GA, 256, 0, stream>>>(dstv, bcnt);
    k_btot<<<GB4, 256, 0, stream>>>(bcnt, tot);
    k_bscanT<<<1, 1024, 0, stream>>>(tot, bbase);
    k_bcur<<<GB4, 256, 0, stream>>>(bcnt, bbase, gcur);
    k_bscatter<<<GA, 256, 0, stream>>>(srcv, dstv, gcur, bpair);
    k_bcsr<<<NBUCK, 256, 0, stream>>>(bpair, bbase, colb, cnt, indptr, dinv);

    // ---- weights ----
    k_wtrans_all<<<(8192 + 32768 + 65536 + 255) / 256, 256, 0, stream>>>(W1, W2, Wf, w1t, w2t, wft);

    // ---- layer 1: scale emb, fused gather+GEMM, BN reduce ----
    k_semb<<<(NN * 16 + 255) / 256, 256, 0, stream>>>(emb, dinv, (uint2*)embs);
    k_aggmm<64, 128, 2, true><<<GX, 256, 0, stream>>>(embs, indptr, cnt, colb, dinv, w1t, H1, b1, partials);
    k_bnred<128><<<8, 256, 0, stream>>>(partials, g1, be1, sc1, sh1);

    // ---- layer 2: BN+leaky+dinv transform, fused gather+GEMM, BN reduce ----
    k_x2s<<<(NN * 16 + 255) / 256, 256, 0, stream>>>(H1, sc1, sh1, dinv, x2s);
    k_aggmm<128, 256, 2, true><<<GX, 256, 0, stream>>>(x2s, indptr, cnt, colb, dinv, w2t, H2, b2, partials);
    k_bnred<256><<<16, 256, 0, stream>>>(partials, g2, be2, sc2, sh2);

    // ---- final linear -> fp32 d_out ----
    k_mgemm<256, 256><<<GX, 256, 0, stream>>>(H2, wft, out, sc2, sh2, bf);
}

// Round 10
// 361.049 us; speedup vs baseline: 1.5990x; 1.5990x over previous
//
#include <hip/hip_runtime.h>

#define NN 100000
#define NE 1600000
constexpr float EPS_BN = 1e-5f;
constexpr float ALPHA = 0.01f;
constexpr int NBUCK = (NN + 127) / 128;     // 782 buckets of 128 nodes
constexpr int GA = 128;                     // bucket-pass blocks
constexpr int EPB = NE / GA;                // 12500 edges/block (exact)
constexpr int GX = (NN + 63) / 64;          // 1563 gemm blocks

typedef __attribute__((ext_vector_type(8))) short short8;
typedef __attribute__((ext_vector_type(4))) float f32x4;

// ---- bf16 helpers ----
__device__ __forceinline__ float bfu2f(uint lo16) {
    union { uint i; float f; } v; v.i = lo16 << 16; return v.f;
}
__device__ __forceinline__ float bfhi2f(uint u) {
    union { uint i; float f; } v; v.i = u & 0xffff0000u; return v.f;
}
__device__ __forceinline__ ushort f2bf(float f) {     // RNE
    union { float f; uint i; } v; v.f = f;
    return (ushort)((v.i + 0x7fffu + ((v.i >> 16) & 1u)) >> 16);
}

// ================= bucketed CSR build =================
__global__ __launch_bounds__(256) void k_bhist(const int* __restrict__ dstv, int* __restrict__ bcnt) {
    __shared__ int hist[NBUCK];
    for (int i = threadIdx.x; i < NBUCK; i += 256) hist[i] = 0;
    __syncthreads();
    int base = blockIdx.x * EPB;
    for (int i = threadIdx.x; i < EPB; i += 256)
        atomicAdd(&hist[dstv[base + i] >> 7], 1);
    __syncthreads();
    for (int i = threadIdx.x; i < NBUCK; i += 256)
        bcnt[blockIdx.x * NBUCK + i] = hist[i];
}

// fused: bucket totals -> scan -> per-(block,bucket) cursors (one block, internal barriers)
__global__ __launch_bounds__(1024) void k_bprep(const int* __restrict__ bcnt,
                                                int* __restrict__ gcur, int* __restrict__ bbase) {
    __shared__ int tmp[1024];
    int b = threadIdx.x;
    int t = 0;
    if (b < NBUCK)
        for (int k = 0; k < GA; ++k) t += bcnt[k * NBUCK + b];   // coalesced across threads
    tmp[b] = t;
    __syncthreads();
    for (int off = 1; off < 1024; off <<= 1) {
        int u = (b >= off) ? tmp[b - off] : 0;
        __syncthreads();
        tmp[b] += u;
        __syncthreads();
    }
    int ex = tmp[b] - t;   // exclusive
    if (b < NBUCK) {
        bbase[b] = ex;
        int cur = ex;
        for (int k = 0; k < GA; ++k) { gcur[k * NBUCK + b] = cur; cur += bcnt[k * NBUCK + b]; }
    }
    if (b == 0) bbase[NBUCK] = NE;
}

__global__ __launch_bounds__(256) void k_bscatter(const int* __restrict__ srcv, const int* __restrict__ dstv,
                                                  const int* __restrict__ gcur, uint* __restrict__ bpair) {
    __shared__ int lcur[NBUCK];
    for (int i = threadIdx.x; i < NBUCK; i += 256) lcur[i] = gcur[blockIdx.x * NBUCK + i];
    __syncthreads();
    int base = blockIdx.x * EPB;
    for (int i = threadIdx.x; i < EPB; i += 256) {
        int d = dstv[base + i], s = srcv[base + i];
        int slot = atomicAdd(&lcur[d >> 7], 1);
        bpair[slot] = ((uint)(d & 127) << 17) | (uint)s;
    }
}

__global__ __launch_bounds__(256) void k_bcsr(const uint* __restrict__ bpair, const int* __restrict__ bbase,
                                              int* __restrict__ col, int* __restrict__ cnt,
                                              int* __restrict__ indptr, float* __restrict__ dinv) {
    __shared__ int h[128];
    __shared__ int off[128];
    int b = blockIdx.x, t = threadIdx.x;
    int p0 = bbase[b], p1 = bbase[b + 1];
    if (t < 128) h[t] = 0;
    __syncthreads();
    for (int i = p0 + t; i < p1; i += 256)
        atomicAdd(&h[bpair[i] >> 17], 1);
    __syncthreads();
    if (t < 128) off[t] = h[t];
    __syncthreads();
    for (int o = 1; o < 128; o <<= 1) {
        int u = 0;
        if (t < 128 && t >= o) u = off[t - o];
        __syncthreads();
        if (t < 128) off[t] += u;
        __syncthreads();
    }
    if (t < 128) {
        int st = p0 + off[t] - h[t];
        int node = b * 128 + t;
        if (node < NN) {
            indptr[node] = st;
            cnt[node] = h[t];
            dinv[node] = rsqrtf((float)(h[t] + 1));   // +1 self loop
        }
        off[t] = st;
    }
    __syncthreads();
    for (int i = p0 + t; i < p1; i += 256) {
        uint u = bpair[i];
        int slot = atomicAdd(&off[u >> 17], 1);
        col[slot] = (int)(u & 0x1FFFFu);
    }
}

// ================= all weights -> bf16 transposed [M][K] =================
__global__ void k_wtrans_all(const float* __restrict__ W1, const float* __restrict__ W2,
                             const float* __restrict__ Wf, ushort* __restrict__ w1t,
                             ushort* __restrict__ w2t, ushort* __restrict__ wft) {
    int i = blockIdx.x * 256 + threadIdx.x;
    if (i < 8192) {                    // W1: 64x128 -> [128][64]
        int m = i / 64, k = i % 64;
        w1t[i] = f2bf(W1[(size_t)k * 128 + m]);
    } else if (i < 8192 + 32768) {     // W2: 128x256 -> [256][128]
        int j = i - 8192;
        int m = j / 128, k = j % 128;
        w2t[j] = f2bf(W2[(size_t)k * 256 + m]);
    } else if (i < 8192 + 32768 + 65536) {   // Wf: 256x256 -> [256][256]
        int j = i - 8192 - 32768;
        int m = j / 256, k = j % 256;
        wft[j] = f2bf(Wf[(size_t)k * 256 + m]);
    }
}

// ================= elementwise pre-passes =================
__global__ __launch_bounds__(256) void k_semb(const float* __restrict__ emb, const float* __restrict__ dinv,
                                              uint2* __restrict__ embs) {
    int i = blockIdx.x * 256 + threadIdx.x;   // uint2 index: 4 feats
    if (i >= NN * 16) return;
    int row = i >> 4;
    float dn = dinv[row];
    float4 f = ((const float4*)emb)[i];
    uint2 o;
    o.x = (uint)f2bf(f.x * dn) | ((uint)f2bf(f.y * dn) << 16);
    o.y = (uint)f2bf(f.z * dn) | ((uint)f2bf(f.w * dn) << 16);
    embs[i] = o;
}

__global__ __launch_bounds__(256) void k_x2s(const ushort* __restrict__ H1, const float* __restrict__ sc,
                                             const float* __restrict__ sh, const float* __restrict__ dinv,
                                             ushort* __restrict__ x2s) {
    int i = blockIdx.x * 256 + threadIdx.x;   // uint4 index: 8 feats
    if (i >= NN * 16) return;
    int row = i >> 4, f0 = (i & 15) * 8;
    float dn = dinv[row];
    uint4 u = ((const uint4*)H1)[i];
    uint uu[4] = {u.x, u.y, u.z, u.w};
    uint oo[4];
#pragma unroll
    for (int q = 0; q < 4; ++q) {
        int f = f0 + q * 2;
        float e0 = bfu2f(uu[q] & 0xffffu) * sc[f] + sh[f];
        float e1 = bfhi2f(uu[q]) * sc[f + 1] + sh[f + 1];
        e0 = ((e0 >= 0.f) ? e0 : ALPHA * e0) * dn;
        e1 = ((e1 >= 0.f) ? e1 : ALPHA * e1) * dn;
        oo[q] = (uint)f2bf(e0) | ((uint)f2bf(e1) << 16);
    }
    uint4 o; o.x = oo[0]; o.y = oo[1]; o.z = oo[2]; o.w = oo[3];
    ((uint4*)x2s)[i] = o;
}

// ================= CSR gather aggregation (1 wave per node — max MLP) =================
__global__ __launch_bounds__(64) void k_agg64(const ushort* __restrict__ X, const int* __restrict__ indptr,
                                              const int* __restrict__ cnt, const int* __restrict__ col,
                                              const float* __restrict__ dinv, ushort* __restrict__ out) {
    int n = blockIdx.x, t = threadIdx.x;
    int t2 = t & 31, h = t >> 5;
    __shared__ int sc[64];
    int start = indptr[n], c = cnt[n];
    const uint* Xu = (const uint*)X;
    float a0 = 0.f, a1 = 0.f;
    if (h == 0) {
        uint u = Xu[(size_t)n * 32 + t2];
        a0 = bfu2f(u & 0xffffu); a1 = bfhi2f(u);
    }
    for (int base = 0; base < c; base += 64) {
        int m = min(64, c - base);
        if (t < m) sc[t] = col[start + base + t];
        __syncthreads();
#pragma unroll 2
        for (int j = h; j < m; j += 2) {
            uint v = Xu[(size_t)sc[j] * 32 + t2];
            a0 += bfu2f(v & 0xffffu); a1 += bfhi2f(v);
        }
        __syncthreads();
    }
    a0 += __shfl_xor(a0, 32);
    a1 += __shfl_xor(a1, 32);
    if (h == 0) {
        float dn = dinv[n];
        ((uint*)out)[(size_t)n * 32 + t2] = (uint)f2bf(a0 * dn) | ((uint)f2bf(a1 * dn) << 16);
    }
}

__global__ __launch_bounds__(64) void k_agg128(const ushort* __restrict__ X, const int* __restrict__ indptr,
                                               const int* __restrict__ cnt, const int* __restrict__ col,
                                               const float* __restrict__ dinv, ushort* __restrict__ out) {
    int n = blockIdx.x, t = threadIdx.x;
    __shared__ int sc[64];
    int start = indptr[n], c = cnt[n];
    const uint* Xu = (const uint*)X;
    uint u = Xu[(size_t)n * 64 + t];
    float a0 = bfu2f(u & 0xffffu), a1 = bfhi2f(u);
    float b0 = 0.f, b1 = 0.f;
    for (int base = 0; base < c; base += 64) {
        int m = min(64, c - base);
        if (t < m) sc[t] = col[start + base + t];
        __syncthreads();
        int j = 0;
#pragma unroll 2
        for (; j + 2 <= m; j += 2) {
            uint v0 = Xu[(size_t)sc[j] * 64 + t];
            uint v1 = Xu[(size_t)sc[j + 1] * 64 + t];
            a0 += bfu2f(v0 & 0xffffu); a1 += bfhi2f(v0);
            b0 += bfu2f(v1 & 0xffffu); b1 += bfhi2f(v1);
        }
        if (j < m) {
            uint v = Xu[(size_t)sc[j] * 64 + t];
            a0 += bfu2f(v & 0xffffu); a1 += bfhi2f(v);
        }
        __syncthreads();
    }
    a0 += b0; a1 += b1;
    float dn = dinv[n];
    ((uint*)out)[(size_t)n * 64 + t] = (uint)f2bf(a0 * dn) | ((uint)f2bf(a1 * dn) << 16);
}

// ================= MFMA bf16 GEMM: BM=64, no B-LDS, dbuf A, fused BN-stats =================
template <int AT>
__device__ __forceinline__ uint4 xform8(uint4 u, int kbase, const float* s_sc, const float* s_sh) {
    if constexpr (AT == 1) {
        uint uu[4] = {u.x, u.y, u.z, u.w};
        uint oo[4];
#pragma unroll
        for (int q = 0; q < 4; ++q) {
            int kq = kbase + q * 2;
            float e0 = bfu2f(uu[q] & 0xffffu) * s_sc[kq] + s_sh[kq];
            float e1 = bfhi2f(uu[q]) * s_sc[kq + 1] + s_sh[kq + 1];
            e0 = (e0 >= 0.f) ? e0 : ALPHA * e0;
            e1 = (e1 >= 0.f) ? e1 : ALPHA * e1;
            oo[q] = (uint)f2bf(e0) | ((uint)f2bf(e1) << 16);
        }
        return make_uint4(oo[0], oo[1], oo[2], oo[3]);
    } else {
        return u;
    }
}

template <int K, int NOUT, int AT, int OUT, bool STATS>
__global__ __launch_bounds__(256) void k_mgemm(
        const void* __restrict__ Ap, const ushort* __restrict__ BT, void* __restrict__ Cp,
        const float* __restrict__ scale, const float* __restrict__ shift,
        const float* __restrict__ bias, float* __restrict__ partials) {
    constexpr int BM = 64, BK = 32, LDA = 40;
    constexpr int WN = NOUT / 4;          // wave col width: 32 or 64
    constexpr int NF = WN / 16;           // col frags/wave: 2 or 4
    constexpr int NT = K / BK;
    __shared__ ushort As[2][BM * LDA];
    __shared__ float s_sc[K];
    __shared__ float s_sh[K];

    int tid = threadIdx.x;
    int brow = blockIdx.x * BM;
    int lane = tid & 63, wid = tid >> 6;
    int fr = lane & 15, fq = lane >> 4;
    int fk = fq * 8;

    const int srow = tid >> 2, sk0 = (tid & 3) * 8;   // A-stage: 8 bf16/thread
    const int grow = brow + srow;
    const bool aok = grow < NN;
    const ushort* arp = (const ushort*)Ap + (size_t)grow * K + sk0;

    if constexpr (AT == 1) {
        for (int i = tid; i < K; i += 256) { s_sc[i] = scale[i]; s_sh[i] = shift[i]; }
        __syncthreads();
    }

    f32x4 acc[4][NF];
#pragma unroll
    for (int mi = 0; mi < 4; ++mi)
#pragma unroll
        for (int ni = 0; ni < NF; ++ni) acc[mi][ni] = (f32x4){0.f, 0.f, 0.f, 0.f};

    // prologue: stage tile 0
    uint4 av = make_uint4(0, 0, 0, 0);
    if (aok) av = *(const uint4*)arp;
    av = xform8<AT>(av, sk0, s_sc, s_sh);
    *(uint4*)&As[0][srow * LDA + sk0] = av;

    for (int t = 0; t < NT; ++t) {
        __syncthreads();                      // As[t&1] ready for all
        uint4 anext = make_uint4(0, 0, 0, 0);
        if (t + 1 < NT && aok)
            anext = *(const uint4*)(arp + (t + 1) * BK);   // issue early (overlaps MFMA)

        short8 bfv[NF];
#pragma unroll
        for (int ni = 0; ni < NF; ++ni)
            bfv[ni] = *(const short8*)(BT + (size_t)(wid * WN + ni * 16 + fr) * K + t * BK + fk);

        short8 af[4];
#pragma unroll
        for (int mi = 0; mi < 4; ++mi)
            af[mi] = *(const short8*)&As[t & 1][(mi * 16 + fr) * LDA + fk];

#pragma unroll
        for (int mi = 0; mi < 4; ++mi)
#pragma unroll
            for (int ni = 0; ni < NF; ++ni)
                acc[mi][ni] = __builtin_amdgcn_mfma_f32_16x16x32_bf16(af[mi], bfv[ni], acc[mi][ni], 0, 0, 0);

        if (t + 1 < NT) {                     // write-late into alternate buffer
            anext = xform8<AT>(anext, (t + 1) * BK + sk0, s_sc, s_sh);
            *(uint4*)&As[(t + 1) & 1][srow * LDA + sk0] = anext;
        }
    }

    float bv[NF];
#pragma unroll
    for (int ni = 0; ni < NF; ++ni) bv[ni] = bias[wid * WN + ni * 16 + fr];

    float sv[NF], qv[NF];
#pragma unroll
    for (int ni = 0; ni < NF; ++ni) { sv[ni] = 0.f; qv[ni] = 0.f; }

#pragma unroll
    for (int mi = 0; mi < 4; ++mi)
#pragma unroll
        for (int r = 0; r < 4; ++r) {
            int row = brow + mi * 16 + fq * 4 + r;
            if (row < NN) {
#pragma unroll
                for (int ni = 0; ni < NF; ++ni) {
                    float x = acc[mi][ni][r] + bv[ni];
                    int c = wid * WN + ni * 16 + fr;
                    if constexpr (OUT == 1)
                        ((float*)Cp)[(size_t)row * NOUT + c] = x;
                    else
                        ((ushort*)Cp)[(size_t)row * NOUT + c] = f2bf(x);
                    if constexpr (STATS) { sv[ni] += x; qv[ni] += x * x; }
                }
            }
        }

    if constexpr (STATS) {
        // reduce over fq groups (lanes fr, fr+16, fr+32, fr+48)
#pragma unroll
        for (int ni = 0; ni < NF; ++ni) {
            sv[ni] += __shfl_down(sv[ni], 32); qv[ni] += __shfl_down(qv[ni], 32);
            sv[ni] += __shfl_down(sv[ni], 16); qv[ni] += __shfl_down(qv[ni], 16);
        }
        if (fq == 0) {
            float* pb = partials + (size_t)blockIdx.x * 2 * NOUT;
#pragma unroll
            for (int ni = 0; ni < NF; ++ni) {
                int c = wid * WN + ni * 16 + fr;
                pb[c] = sv[ni];
                pb[NOUT + c] = qv[ni];
            }
        }
    }
}

// ================= BN reduce: partials[GX][2M] -> scale/shift =================
template <int M>
__global__ __launch_bounds__(256) void k_bnred(const float* __restrict__ partials, const float* __restrict__ g,
                                               const float* __restrict__ be, float* __restrict__ scale,
                                               float* __restrict__ shift) {
    int tid = threadIdx.x;
    int fl = tid & 15, bl = tid >> 4;
    int f = blockIdx.x * 16 + fl;
    float s = 0.f, q = 0.f;
    for (int b = bl; b < GX; b += 16) {
        s += partials[(size_t)b * 2 * M + f];
        q += partials[(size_t)b * 2 * M + M + f];
    }
    __shared__ float rs[256], rq[256];
    rs[tid] = s; rq[tid] = q;
    __syncthreads();
    for (int h = 128; h >= 16; h >>= 1) {
        if (tid < h) { rs[tid] += rs[tid + h]; rq[tid] += rq[tid + h]; }
        __syncthreads();
    }
    if (tid < 16) {
        float su = rs[tid], qu = rq[tid];
        float mu = su * (1.f / NN);
        float var = qu * (1.f / NN) - mu * mu;
        float r = rsqrtf(var + EPS_BN);
        float sc = g[f] * r;
        scale[f] = sc;
        shift[f] = be[f] - mu * sc;
    }
}

// ================= launch =================
extern "C" void kernel_launch(void* const* d_in, const int* in_sizes, int n_in,
                              void* d_out, int out_size, void* d_ws, size_t ws_size,
                              hipStream_t stream) {
    const float* emb = (const float*)d_in[0];
    const int* eidx  = (const int*)d_in[1];
    const float* W1  = (const float*)d_in[2];
    const float* b1  = (const float*)d_in[3];
    const float* g1  = (const float*)d_in[4];
    const float* be1 = (const float*)d_in[5];
    const float* W2  = (const float*)d_in[6];
    const float* b2  = (const float*)d_in[7];
    const float* g2  = (const float*)d_in[8];
    const float* be2 = (const float*)d_in[9];
    const float* Wf  = (const float*)d_in[10];
    const float* bf  = (const float*)d_in[11];
    float* out = (float*)d_out;
    const int* srcv = eidx;
    const int* dstv = eidx + NE;

    char* w = (char*)d_ws;
    auto alloc = [&](size_t bytes) {
        char* p = w;
        w += (bytes + 255) / 256 * 256;
        return p;
    };
    int* cnt    = (int*)alloc((size_t)NN * 4);
    int* indptr = (int*)alloc((size_t)NN * 4);
    int* bcnt   = (int*)alloc((size_t)NBUCK * GA * 4);
    int* gcur   = (int*)alloc((size_t)NBUCK * GA * 4);
    int* bbase  = (int*)alloc((size_t)(NBUCK + 1) * 4);
    int* colb   = (int*)alloc((size_t)NE * 4);
    uint* bpair = (uint*)alloc((size_t)NE * 4);
    float* dinv = (float*)alloc((size_t)NN * 4);
    float* partials = (float*)alloc((size_t)GX * 512 * 4);
    float* sc1 = (float*)alloc(128 * 4);
    float* sh1 = (float*)alloc(128 * 4);
    float* sc2 = (float*)alloc(256 * 4);
    float* sh2 = (float*)alloc(256 * 4);
    ushort* w1t = (ushort*)alloc((size_t)128 * 64 * 2);
    ushort* w2t = (ushort*)alloc((size_t)256 * 128 * 2);
    ushort* wft = (ushort*)alloc((size_t)256 * 256 * 2);
    ushort* slabA = (ushort*)alloc((size_t)NN * 128 * 2);   // embs -> H1 -> agg2
    ushort* slabB = (ushort*)alloc((size_t)NN * 128 * 2);   // aggE -> x2s
    ushort* H2 = (ushort*)alloc((size_t)NN * 256 * 2);

    ushort* embs = slabA;
    ushort* aggE = slabB;
    ushort* H1   = slabA;
    ushort* x2s  = slabB;
    ushort* agg2 = slabA;

    // ---- CSR build ----
    k_bhist<<<GA, 256, 0, stream>>>(dstv, bcnt);
    k_bprep<<<1, 1024, 0, stream>>>(bcnt, gcur, bbase);
    k_bscatter<<<GA, 256, 0, stream>>>(srcv, dstv, gcur, bpair);
    k_bcsr<<<NBUCK, 256, 0, stream>>>(bpair, bbase, colb, cnt, indptr, dinv);

    // ---- weights ----
    k_wtrans_all<<<(8192 + 32768 + 65536 + 255) / 256, 256, 0, stream>>>(W1, W2, Wf, w1t, w2t, wft);

    // ---- layer 1 ----
    k_semb<<<(NN * 16 + 255) / 256, 256, 0, stream>>>(emb, dinv, (uint2*)embs);
    k_agg64<<<NN, 64, 0, stream>>>(embs, indptr, cnt, colb, dinv, aggE);
    k_mgemm<64, 128, 2, 2, true><<<GX, 256, 0, stream>>>(aggE, w1t, H1, nullptr, nullptr, b1, partials);
    k_bnred<128><<<8, 256, 0, stream>>>(partials, g1, be1, sc1, sh1);

    // ---- layer 2 ----
    k_x2s<<<(NN * 16 + 255) / 256, 256, 0, stream>>>(H1, sc1, sh1, dinv, x2s);
    k_agg128<<<NN, 64, 0, stream>>>(x2s, indptr, cnt, colb, dinv, agg2);
    k_mgemm<128, 256, 2, 2, true><<<GX, 256, 0, stream>>>(agg2, w2t, H2, nullptr, nullptr, b2, partials);
    k_bnred<256><<<16, 256, 0, stream>>>(partials, g2, be2, sc2, sh2);

    // ---- final linear -> fp32 d_out ----
    k_mgemm<256, 256, 1, 1, false><<<GX, 256, 0, stream>>>(H2, wft, out, sc2, sh2, bf, nullptr);
}

// Round 11
// 353.520 us; speedup vs baseline: 1.6331x; 1.0213x over previous
//
#include <hip/hip_runtime.h>

#define NN 100000
#define NE 1600000
constexpr float EPS_BN = 1e-5f;
constexpr float ALPHA = 0.01f;
constexpr int NBUCK = (NN + 127) / 128;     // 782 buckets of 128 nodes
constexpr int GA = 128;                     // bucket-pass blocks
constexpr int EPB = NE / GA;                // 12500 edges/block (exact)
constexpr int GX = (NN + 63) / 64;          // 1563 gemm blocks
constexpr int WT_ELEMS = 8192 + 32768 + 65536;       // 106496
constexpr int WT_BLKS = (WT_ELEMS + 255) / 256;      // 416

typedef __attribute__((ext_vector_type(8))) short short8;
typedef __attribute__((ext_vector_type(4))) float f32x4;

// ---- bf16 helpers ----
__device__ __forceinline__ float bfu2f(uint lo16) {
    union { uint i; float f; } v; v.i = lo16 << 16; return v.f;
}
__device__ __forceinline__ float bfhi2f(uint u) {
    union { uint i; float f; } v; v.i = u & 0xffff0000u; return v.f;
}
__device__ __forceinline__ ushort f2bf(float f) {     // RNE
    union { float f; uint i; } v; v.f = f;
    return (ushort)((v.i + 0x7fffu + ((v.i >> 16) & 1u)) >> 16);
}

// ================= bhist + weight transpose, one launch (independent work) =================
__global__ __launch_bounds__(256) void k_bhist_wt(const int* __restrict__ dstv, int* __restrict__ bcnt,
                                                  const float* __restrict__ W1, const float* __restrict__ W2,
                                                  const float* __restrict__ Wf, ushort* __restrict__ w1t,
                                                  ushort* __restrict__ w2t, ushort* __restrict__ wft) {
    if (blockIdx.x < GA) {
        __shared__ int hist[NBUCK];
        for (int i = threadIdx.x; i < NBUCK; i += 256) hist[i] = 0;
        __syncthreads();
        int base = blockIdx.x * EPB;
        for (int i = threadIdx.x; i < EPB; i += 256)
            atomicAdd(&hist[dstv[base + i] >> 7], 1);
        __syncthreads();
        for (int i = threadIdx.x; i < NBUCK; i += 256)
            bcnt[blockIdx.x * NBUCK + i] = hist[i];
    } else {
        int i = (blockIdx.x - GA) * 256 + threadIdx.x;
        if (i < 8192) {                    // W1: 64x128 -> [128][64]
            int m = i / 64, k = i % 64;
            w1t[i] = f2bf(W1[(size_t)k * 128 + m]);
        } else if (i < 8192 + 32768) {     // W2: 128x256 -> [256][128]
            int j = i - 8192;
            int m = j / 128, k = j % 128;
            w2t[j] = f2bf(W2[(size_t)k * 256 + m]);
        } else if (i < WT_ELEMS) {         // Wf: 256x256 -> [256][256]
            int j = i - 8192 - 32768;
            int m = j / 256, k = j % 256;
            wft[j] = f2bf(Wf[(size_t)k * 256 + m]);
        }
    }
}

// totals per bucket (coalesced, multi-block)
__global__ __launch_bounds__(256) void k_btot(const int* __restrict__ bcnt, int* __restrict__ tot) {
    int b = blockIdx.x * 256 + threadIdx.x;
    if (b < NBUCK) {
        int t = 0;
        for (int k = 0; k < GA; ++k) t += bcnt[k * NBUCK + b];
        tot[b] = t;
    }
}

// scan 782 totals -> bbase (tiny single block)
__global__ __launch_bounds__(1024) void k_bscanT(const int* __restrict__ tot, int* __restrict__ bbase) {
    __shared__ int tmp[1024];
    int b = threadIdx.x;
    int v = (b < NBUCK) ? tot[b] : 0;
    tmp[b] = v;
    __syncthreads();
    for (int off = 1; off < 1024; off <<= 1) {
        int u = (b >= off) ? tmp[b - off] : 0;
        __syncthreads();
        tmp[b] += u;
        __syncthreads();
    }
    if (b < NBUCK) bbase[b] = tmp[b] - v;
    if (b == 0) bbase[NBUCK] = NE;
}

// per-(block,bucket) cursors (multi-block)
__global__ __launch_bounds__(256) void k_bcur(const int* __restrict__ bcnt, const int* __restrict__ bbase,
                                              int* __restrict__ gcur) {
    int b = blockIdx.x * 256 + threadIdx.x;
    if (b < NBUCK) {
        int cur = bbase[b];
        for (int k = 0; k < GA; ++k) { gcur[k * NBUCK + b] = cur; cur += bcnt[k * NBUCK + b]; }
    }
}

__global__ __launch_bounds__(256) void k_bscatter(const int* __restrict__ srcv, const int* __restrict__ dstv,
                                                  const int* __restrict__ gcur, uint* __restrict__ bpair) {
    __shared__ int lcur[NBUCK];
    for (int i = threadIdx.x; i < NBUCK; i += 256) lcur[i] = gcur[blockIdx.x * NBUCK + i];
    __syncthreads();
    int base = blockIdx.x * EPB;
    for (int i = threadIdx.x; i < EPB; i += 256) {
        int d = dstv[base + i], s = srcv[base + i];
        int slot = atomicAdd(&lcur[d >> 7], 1);
        bpair[slot] = ((uint)(d & 127) << 17) | (uint)s;
    }
}

__global__ __launch_bounds__(256) void k_bcsr(const uint* __restrict__ bpair, const int* __restrict__ bbase,
                                              int* __restrict__ col, int* __restrict__ cnt,
                                              int* __restrict__ indptr, float* __restrict__ dinv) {
    __shared__ int h[128];
    __shared__ int off[128];
    int b = blockIdx.x, t = threadIdx.x;
    int p0 = bbase[b], p1 = bbase[b + 1];
    if (t < 128) h[t] = 0;
    __syncthreads();
    for (int i = p0 + t; i < p1; i += 256)
        atomicAdd(&h[bpair[i] >> 17], 1);
    __syncthreads();
    if (t < 128) off[t] = h[t];
    __syncthreads();
    for (int o = 1; o < 128; o <<= 1) {
        int u = 0;
        if (t < 128 && t >= o) u = off[t - o];
        __syncthreads();
        if (t < 128) off[t] += u;
        __syncthreads();
    }
    if (t < 128) {
        int st = p0 + off[t] - h[t];
        int node = b * 128 + t;
        if (node < NN) {
            indptr[node] = st;
            cnt[node] = h[t];
            dinv[node] = rsqrtf((float)(h[t] + 1));   // +1 self loop
        }
        off[t] = st;
    }
    __syncthreads();
    for (int i = p0 + t; i < p1; i += 256) {
        uint u = bpair[i];
        int slot = atomicAdd(&off[u >> 17], 1);
        col[slot] = (int)(u & 0x1FFFFu);
    }
}

// ================= elementwise pre-passes =================
__global__ __launch_bounds__(256) void k_semb(const float* __restrict__ emb, const float* __restrict__ dinv,
                                              uint2* __restrict__ embs) {
    int i = blockIdx.x * 256 + threadIdx.x;   // uint2 index: 4 feats
    if (i >= NN * 16) return;
    int row = i >> 4;
    float dn = dinv[row];
    float4 f = ((const float4*)emb)[i];
    uint2 o;
    o.x = (uint)f2bf(f.x * dn) | ((uint)f2bf(f.y * dn) << 16);
    o.y = (uint)f2bf(f.z * dn) | ((uint)f2bf(f.w * dn) << 16);
    embs[i] = o;
}

__global__ __launch_bounds__(256) void k_x2s(const ushort* __restrict__ H1, const float* __restrict__ sc,
                                             const float* __restrict__ sh, const float* __restrict__ dinv,
                                             ushort* __restrict__ x2s) {
    int i = blockIdx.x * 256 + threadIdx.x;   // uint4 index: 8 feats
    if (i >= NN * 16) return;
    int row = i >> 4, f0 = (i & 15) * 8;
    float dn = dinv[row];
    uint4 u = ((const uint4*)H1)[i];
    uint uu[4] = {u.x, u.y, u.z, u.w};
    uint oo[4];
#pragma unroll
    for (int q = 0; q < 4; ++q) {
        int f = f0 + q * 2;
        float e0 = bfu2f(uu[q] & 0xffffu) * sc[f] + sh[f];
        float e1 = bfhi2f(uu[q]) * sc[f + 1] + sh[f + 1];
        e0 = ((e0 >= 0.f) ? e0 : ALPHA * e0) * dn;
        e1 = ((e1 >= 0.f) ? e1 : ALPHA * e1) * dn;
        oo[q] = (uint)f2bf(e0) | ((uint)f2bf(e1) << 16);
    }
    uint4 o; o.x = oo[0]; o.y = oo[1]; o.z = oo[2]; o.w = oo[3];
    ((uint4*)x2s)[i] = o;
}

// ================= CSR gather aggregation (1 wave per node — max MLP) =================
__global__ __launch_bounds__(64) void k_agg64(const ushort* __restrict__ X, const int* __restrict__ indptr,
                                              const int* __restrict__ cnt, const int* __restrict__ col,
                                              const float* __restrict__ dinv, ushort* __restrict__ out) {
    int n = blockIdx.x, t = threadIdx.x;
    int t2 = t & 31, h = t >> 5;
    __shared__ int sc[64];
    int start = indptr[n], c = cnt[n];
    const uint* Xu = (const uint*)X;
    float a0 = 0.f, a1 = 0.f;
    if (h == 0) {
        uint u = Xu[(size_t)n * 32 + t2];
        a0 = bfu2f(u & 0xffffu); a1 = bfhi2f(u);
    }
    for (int base = 0; base < c; base += 64) {
        int m = min(64, c - base);
        if (t < m) sc[t] = col[start + base + t];
        __syncthreads();
#pragma unroll 2
        for (int j = h; j < m; j += 2) {
            uint v = Xu[(size_t)sc[j] * 32 + t2];
            a0 += bfu2f(v & 0xffffu); a1 += bfhi2f(v);
        }
        __syncthreads();
    }
    a0 += __shfl_xor(a0, 32);
    a1 += __shfl_xor(a1, 32);
    if (h == 0) {
        float dn = dinv[n];
        ((uint*)out)[(size_t)n * 32 + t2] = (uint)f2bf(a0 * dn) | ((uint)f2bf(a1 * dn) << 16);
    }
}

__global__ __launch_bounds__(64) void k_agg128(const ushort* __restrict__ X, const int* __restrict__ indptr,
                                               const int* __restrict__ cnt, const int* __restrict__ col,
                                               const float* __restrict__ dinv, ushort* __restrict__ out) {
    int n = blockIdx.x, t = threadIdx.x;
    __shared__ int sc[64];
    int start = indptr[n], c = cnt[n];
    const uint* Xu = (const uint*)X;
    uint u = Xu[(size_t)n * 64 + t];
    float a0 = bfu2f(u & 0xffffu), a1 = bfhi2f(u);
    float b0 = 0.f, b1 = 0.f;
    for (int base = 0; base < c; base += 64) {
        int m = min(64, c - base);
        if (t < m) sc[t] = col[start + base + t];
        __syncthreads();
        int j = 0;
#pragma unroll 2
        for (; j + 2 <= m; j += 2) {
            uint v0 = Xu[(size_t)sc[j] * 64 + t];
            uint v1 = Xu[(size_t)sc[j + 1] * 64 + t];
            a0 += bfu2f(v0 & 0xffffu); a1 += bfhi2f(v0);
            b0 += bfu2f(v1 & 0xffffu); b1 += bfhi2f(v1);
        }
        if (j < m) {
            uint v = Xu[(size_t)sc[j] * 64 + t];
            a0 += bfu2f(v & 0xffffu); a1 += bfhi2f(v);
        }
        __syncthreads();
    }
    a0 += b0; a1 += b1;
    float dn = dinv[n];
    ((uint*)out)[(size_t)n * 64 + t] = (uint)f2bf(a0 * dn) | ((uint)f2bf(a1 * dn) << 16);
}

// ================= MFMA bf16 GEMM: BM=64, no B-LDS, dbuf A, fused BN-stats =================
template <int AT>
__device__ __forceinline__ uint4 xform8(uint4 u, int kbase, const float* s_sc, const float* s_sh) {
    if constexpr (AT == 1) {
        uint uu[4] = {u.x, u.y, u.z, u.w};
        uint oo[4];
#pragma unroll
        for (int q = 0; q < 4; ++q) {
            int kq = kbase + q * 2;
            float e0 = bfu2f(uu[q] & 0xffffu) * s_sc[kq] + s_sh[kq];
            float e1 = bfhi2f(uu[q]) * s_sc[kq + 1] + s_sh[kq + 1];
            e0 = (e0 >= 0.f) ? e0 : ALPHA * e0;
            e1 = (e1 >= 0.f) ? e1 : ALPHA * e1;
            oo[q] = (uint)f2bf(e0) | ((uint)f2bf(e1) << 16);
        }
        return make_uint4(oo[0], oo[1], oo[2], oo[3]);
    } else {
        return u;
    }
}

template <int K, int NOUT, int AT, int OUT, bool STATS>
__global__ __launch_bounds__(256) void k_mgemm(
        const void* __restrict__ Ap, const ushort* __restrict__ BT, void* __restrict__ Cp,
        const float* __restrict__ scale, const float* __restrict__ shift,
        const float* __restrict__ bias, float* __restrict__ partials) {
    constexpr int BM = 64, BK = 32, LDA = 40;
    constexpr int WN = NOUT / 4;          // wave col width: 32 or 64
    constexpr int NF = WN / 16;           // col frags/wave: 2 or 4
    constexpr int NT = K / BK;
    __shared__ ushort As[2][BM * LDA];
    __shared__ float s_sc[K];
    __shared__ float s_sh[K];

    int tid = threadIdx.x;
    int brow = blockIdx.x * BM;
    int lane = tid & 63, wid = tid >> 6;
    int fr = lane & 15, fq = lane >> 4;
    int fk = fq * 8;

    const int srow = tid >> 2, sk0 = (tid & 3) * 8;   // A-stage: 8 bf16/thread
    const int grow = brow + srow;
    const bool aok = grow < NN;
    const ushort* arp = (const ushort*)Ap + (size_t)grow * K + sk0;

    if constexpr (AT == 1) {
        for (int i = tid; i < K; i += 256) { s_sc[i] = scale[i]; s_sh[i] = shift[i]; }
        __syncthreads();
    }

    f32x4 acc[4][NF];
#pragma unroll
    for (int mi = 0; mi < 4; ++mi)
#pragma unroll
        for (int ni = 0; ni < NF; ++ni) acc[mi][ni] = (f32x4){0.f, 0.f, 0.f, 0.f};

    // prologue: stage tile 0
    uint4 av = make_uint4(0, 0, 0, 0);
    if (aok) av = *(const uint4*)arp;
    av = xform8<AT>(av, sk0, s_sc, s_sh);
    *(uint4*)&As[0][srow * LDA + sk0] = av;

    for (int t = 0; t < NT; ++t) {
        __syncthreads();                      // As[t&1] ready for all
        uint4 anext = make_uint4(0, 0, 0, 0);
        if (t + 1 < NT && aok)
            anext = *(const uint4*)(arp + (t + 1) * BK);   // issue early (overlaps MFMA)

        short8 bfv[NF];
#pragma unroll
        for (int ni = 0; ni < NF; ++ni)
            bfv[ni] = *(const short8*)(BT + (size_t)(wid * WN + ni * 16 + fr) * K + t * BK + fk);

        short8 af[4];
#pragma unroll
        for (int mi = 0; mi < 4; ++mi)
            af[mi] = *(const short8*)&As[t & 1][(mi * 16 + fr) * LDA + fk];

#pragma unroll
        for (int mi = 0; mi < 4; ++mi)
#pragma unroll
            for (int ni = 0; ni < NF; ++ni)
                acc[mi][ni] = __builtin_amdgcn_mfma_f32_16x16x32_bf16(af[mi], bfv[ni], acc[mi][ni], 0, 0, 0);

        if (t + 1 < NT) {                     // write-late into alternate buffer
            anext = xform8<AT>(anext, (t + 1) * BK + sk0, s_sc, s_sh);
            *(uint4*)&As[(t + 1) & 1][srow * LDA + sk0] = anext;
        }
    }

    float bv[NF];
#pragma unroll
    for (int ni = 0; ni < NF; ++ni) bv[ni] = bias[wid * WN + ni * 16 + fr];

    float sv[NF], qv[NF];
#pragma unroll
    for (int ni = 0; ni < NF; ++ni) { sv[ni] = 0.f; qv[ni] = 0.f; }

#pragma unroll
    for (int mi = 0; mi < 4; ++mi)
#pragma unroll
        for (int r = 0; r < 4; ++r) {
            int row = brow + mi * 16 + fq * 4 + r;
            if (row < NN) {
#pragma unroll
                for (int ni = 0; ni < NF; ++ni) {
                    float x = acc[mi][ni][r] + bv[ni];
                    int c = wid * WN + ni * 16 + fr;
                    if constexpr (OUT == 1)
                        ((float*)Cp)[(size_t)row * NOUT + c] = x;
                    else
                        ((ushort*)Cp)[(size_t)row * NOUT + c] = f2bf(x);
                    if constexpr (STATS) { sv[ni] += x; qv[ni] += x * x; }
                }
            }
        }

    if constexpr (STATS) {
        // reduce over fq groups (lanes fr, fr+16, fr+32, fr+48)
#pragma unroll
        for (int ni = 0; ni < NF; ++ni) {
            sv[ni] += __shfl_down(sv[ni], 32); qv[ni] += __shfl_down(qv[ni], 32);
            sv[ni] += __shfl_down(sv[ni], 16); qv[ni] += __shfl_down(qv[ni], 16);
        }
        if (fq == 0) {
            float* pb = partials + (size_t)blockIdx.x * 2 * NOUT;
#pragma unroll
            for (int ni = 0; ni < NF; ++ni) {
                int c = wid * WN + ni * 16 + fr;
                pb[c] = sv[ni];
                pb[NOUT + c] = qv[ni];
            }
        }
    }
}

// ================= BN reduce: partials[GX][2M] -> scale/shift =================
template <int M>
__global__ __launch_bounds__(256) void k_bnred(const float* __restrict__ partials, const float* __restrict__ g,
                                               const float* __restrict__ be, float* __restrict__ scale,
                                               float* __restrict__ shift) {
    int tid = threadIdx.x;
    int fl = tid & 15, bl = tid >> 4;
    int f = blockIdx.x * 16 + fl;
    float s = 0.f, q = 0.f;
    for (int b = bl; b < GX; b += 16) {
        s += partials[(size_t)b * 2 * M + f];
        q += partials[(size_t)b * 2 * M + M + f];
    }
    __shared__ float rs[256], rq[256];
    rs[tid] = s; rq[tid] = q;
    __syncthreads();
    for (int h = 128; h >= 16; h >>= 1) {
        if (tid < h) { rs[tid] += rs[tid + h]; rq[tid] += rq[tid + h]; }
        __syncthreads();
    }
    if (tid < 16) {
        float su = rs[tid], qu = rq[tid];
        float mu = su * (1.f / NN);
        float var = qu * (1.f / NN) - mu * mu;
        float r = rsqrtf(var + EPS_BN);
        float sc = g[f] * r;
        scale[f] = sc;
        shift[f] = be[f] - mu * sc;
    }
}

// ================= launch =================
extern "C" void kernel_launch(void* const* d_in, const int* in_sizes, int n_in,
                              void* d_out, int out_size, void* d_ws, size_t ws_size,
                              hipStream_t stream) {
    const float* emb = (const float*)d_in[0];
    const int* eidx  = (const int*)d_in[1];
    const float* W1  = (const float*)d_in[2];
    const float* b1  = (const float*)d_in[3];
    const float* g1  = (const float*)d_in[4];
    const float* be1 = (const float*)d_in[5];
    const float* W2  = (const float*)d_in[6];
    const float* b2  = (const float*)d_in[7];
    const float* g2  = (const float*)d_in[8];
    const float* be2 = (const float*)d_in[9];
    const float* Wf  = (const float*)d_in[10];
    const float* bf  = (const float*)d_in[11];
    float* out = (float*)d_out;
    const int* srcv = eidx;
    const int* dstv = eidx + NE;

    char* w = (char*)d_ws;
    auto alloc = [&](size_t bytes) {
        char* p = w;
        w += (bytes + 255) / 256 * 256;
        return p;
    };
    int* cnt    = (int*)alloc((size_t)NN * 4);
    int* indptr = (int*)alloc((size_t)NN * 4);
    int* bcnt   = (int*)alloc((size_t)NBUCK * GA * 4);
    int* gcur   = (int*)alloc((size_t)NBUCK * GA * 4);
    int* tot    = (int*)alloc((size_t)NBUCK * 4);
    int* bbase  = (int*)alloc((size_t)(NBUCK + 1) * 4);
    int* colb   = (int*)alloc((size_t)NE * 4);
    uint* bpair = (uint*)alloc((size_t)NE * 4);
    float* dinv = (float*)alloc((size_t)NN * 4);
    float* partials = (float*)alloc((size_t)GX * 512 * 4);
    float* sc1 = (float*)alloc(128 * 4);
    float* sh1 = (float*)alloc(128 * 4);
    float* sc2 = (float*)alloc(256 * 4);
    float* sh2 = (float*)alloc(256 * 4);
    ushort* w1t = (ushort*)alloc((size_t)128 * 64 * 2);
    ushort* w2t = (ushort*)alloc((size_t)256 * 128 * 2);
    ushort* wft = (ushort*)alloc((size_t)256 * 256 * 2);
    ushort* slabA = (ushort*)alloc((size_t)NN * 128 * 2);   // embs -> H1 -> agg2
    ushort* slabB = (ushort*)alloc((size_t)NN * 128 * 2);   // aggE -> x2s
    ushort* H2 = (ushort*)alloc((size_t)NN * 256 * 2);

    ushort* embs = slabA;
    ushort* aggE = slabB;
    ushort* H1   = slabA;
    ushort* x2s  = slabB;
    ushort* agg2 = slabA;

    constexpr int GB4 = (NBUCK + 255) / 256;   // 4

    // ---- CSR build (+ weight transpose piggybacked on bhist launch) ----
    k_bhist_wt<<<GA + WT_BLKS, 256, 0, stream>>>(dstv, bcnt, W1, W2, Wf, w1t, w2t, wft);
    k_btot<<<GB4, 256, 0, stream>>>(bcnt, tot);
    k_bscanT<<<1, 1024, 0, stream>>>(tot, bbase);
    k_bcur<<<GB4, 256, 0, stream>>>(bcnt, bbase, gcur);
    k_bscatter<<<GA, 256, 0, stream>>>(srcv, dstv, gcur, bpair);
    k_bcsr<<<NBUCK, 256, 0, stream>>>(bpair, bbase, colb, cnt, indptr, dinv);

    // ---- layer 1 ----
    k_semb<<<(NN * 16 + 255) / 256, 256, 0, stream>>>(emb, dinv, (uint2*)embs);
    k_agg64<<<NN, 64, 0, stream>>>(embs, indptr, cnt, colb, dinv, aggE);
    k_mgemm<64, 128, 2, 2, true><<<GX, 256, 0, stream>>>(aggE, w1t, H1, nullptr, nullptr, b1, partials);
    k_bnred<128><<<8, 256, 0, stream>>>(partials, g1, be1, sc1, sh1);

    // ---- layer 2 ----
    k_x2s<<<(NN * 16 + 255) / 256, 256, 0, stream>>>(H1, sc1, sh1, dinv, x2s);
    k_agg128<<<NN, 64, 0, stream>>>(x2s, indptr, cnt, colb, dinv, agg2);
    k_mgemm<128, 256, 2, 2, true><<<GX, 256, 0, stream>>>(agg2, w2t, H2, nullptr, nullptr, b2, partials);
    k_bnred<256><<<16, 256, 0, stream>>>(partials, g2, be2, sc2, sh2);

    // ---- final linear -> fp32 d_out ----
    k_mgemm<256, 256, 1, 1, false><<<GX, 256, 0, stream>>>(H2, wft, out, sc2, sh2, bf, nullptr);
}